// Round 3
// baseline (513.111 us; speedup 1.0000x reference)
//
#include <hip/hip_runtime.h>
#include <hip/hip_cooperative_groups.h>
#include <math.h>

namespace cg = cooperative_groups;

// Problem constants (B,S,H,D,P fixed by the reference).
#define B_ 16
#define S_ 512
#define H_ 12
#define D_ 768
#define P_ 256
#define K_ 51
#define CH_ 16            // s-rows per phase-2 chunk
#define NCHUNK_ (S_/CH_)  // 32
#define GRID_ 512         // 2 blocks/CU on 256 CUs -> cooperative co-residency safe
#define RPW_ 4            // rows per wave in phase 1: 8192 / (512*4 waves)

// Monotonic float->uint key: larger float <=> larger unsigned.
__device__ __forceinline__ unsigned okey(float f) {
  unsigned u = __float_as_uint(f);
  return (u & 0x80000000u) ? ~u : (u | 0x80000000u);
}

// Shared memory reused across phases (phases separated by grid sync).
union SharedU {
  struct {  // phase 2: colsum + weighted sum staging
    unsigned long long ld[S_ * 4];  // 16 KB
    float inv[S_];                  // 2 KB
    float part[16][8];
    float cs[CH_];
  } p2;
  struct {  // phase 3: tail
    float xs[D_];
    float ts[P_];
    float red[4];
  } p3;
};

// Single cooperative kernel: phase1 (head-avg + exact top-K -> bitmask),
// grid sync, phase2 (colsum -> coef -> weighted hidden partial sums),
// grid sync, phase3 (chunk-sum -> node_trans -> tanh -> fc -> LayerNorm).
__global__ __launch_bounds__(256) void fused_all(
    const float* __restrict__ attn, const float* __restrict__ hidden,
    const float* __restrict__ W_node, const float* __restrict__ b_node,
    const float* __restrict__ node_eta, const float* __restrict__ W_fc,
    const float* __restrict__ b_fc, const float* __restrict__ gamma,
    const float* __restrict__ beta, float* __restrict__ out,
    unsigned long long* __restrict__ maskbuf, float* __restrict__ invbuf,
    float* __restrict__ x_part) {
  __shared__ SharedU sh;
  const int tid = threadIdx.x;
  const int wv = tid >> 6;
  const int lane = tid & 63;
  const int wgid = blockIdx.x * 4 + wv;  // 0..2047

  // ================= phase 1: per-row top-K mask =================
  #pragma unroll 1
  for (int r = 0; r < RPW_; ++r) {
    const int bt = wgid + 2048 * r;   // 0..8191
    const int b = bt >> 9;            // S_ == 512
    const int t = bt & (S_ - 1);

    // --- head-average: lane owns columns {4*lane+i, 256+4*lane+i} ---
    const float* base = attn + (((size_t)b * H_) * S_ + t) * S_;
    float a[8] = {0.f, 0.f, 0.f, 0.f, 0.f, 0.f, 0.f, 0.f};
    #pragma unroll
    for (int h = 0; h < H_; ++h) {
      const float* rp = base + (size_t)h * (S_ * S_);
      const float4 u = *(const float4*)(rp + 4 * lane);
      const float4 v = *(const float4*)(rp + 256 + 4 * lane);
      a[0] += u.x; a[1] += u.y; a[2] += u.z; a[3] += u.w;
      a[4] += v.x; a[5] += v.y; a[6] += v.z; a[7] += v.w;
    }
    unsigned k[8];
    #pragma unroll
    for (int i = 0; i < 8; ++i) {
      a[i] *= (1.0f / (float)H_);
      k[i] = okey(a[i]);
    }

    // --- row-wide positive count via ballots (wave-uniform result) ---
    int p = 0;
    #pragma unroll
    for (int i = 0; i < 8; ++i) p += __popcll(__ballot(a[i] > 0.f));

    bool sel[8];
    float invcnt;
    if (p >= 1 && p < K_) {
      #pragma unroll
      for (int i = 0; i < 8; ++i) sel[i] = (a[i] > 0.f);
      invcnt = 1.0f / (float)p;
    } else {
      // Exact top-K via bitwise radix bisection (wave-uniform control flow).
      unsigned prefix = 0;
      int rem = K_;
      bool done = false;
      unsigned dmask = 0, thr = 0;
      for (int bpos = 31; bpos >= 0; --bpos) {
        const unsigned bit = 1u << bpos;
        const unsigned mb = ~(bit - 1u);       // bits bpos..31
        const unsigned cand = prefix | bit;
        int cnt = 0;
        #pragma unroll
        for (int i = 0; i < 8; ++i)
          cnt += __popcll(__ballot((k[i] & mb) == cand));
        if (cnt == rem) { done = true; dmask = mb; thr = cand; break; }
        if (cnt > rem) prefix = cand;
        else rem -= cnt;
      }
      if (done) {
        #pragma unroll
        for (int i = 0; i < 8; ++i) sel[i] = (k[i] & dmask) >= thr;
      } else {
        // Full-key ties: keep all k > T plus `rem` lowest-index ties.
        const unsigned T = prefix;
        unsigned long long mm[8];
        #pragma unroll
        for (int i = 0; i < 8; ++i) mm[i] = __ballot(k[i] == T);
        const unsigned long long lt = ((unsigned long long)1 << lane) - 1ull;
        int fh = 0;
        #pragma unroll
        for (int i = 0; i < 4; ++i) fh += __popcll(mm[i]);
        #pragma unroll
        for (int i = 0; i < 8; ++i) {
          sel[i] = (k[i] > T);
          if (k[i] == T) {
            int rr = 0;
            if (i < 4) {
              #pragma unroll
              for (int i2 = 0; i2 < 4; ++i2) rr += __popcll(mm[i2] & lt);
              for (int i2 = 0; i2 < i; ++i2) rr += (int)((mm[i2] >> lane) & 1ull);
            } else {
              rr = fh;
              #pragma unroll
              for (int i2 = 4; i2 < 8; ++i2) rr += __popcll(mm[i2] & lt);
              for (int i2 = 4; i2 < i; ++i2) rr += (int)((mm[i2] >> lane) & 1ull);
            }
            if (rr < rem) sel[i] = true;
          }
        }
      }
      invcnt = 1.0f / (float)K_;
    }

    unsigned long long m[8];
    #pragma unroll
    for (int i = 0; i < 8; ++i) m[i] = __ballot(sel[i]);
    if (lane == 0) {
      ulonglong2* mp = (ulonglong2*)(maskbuf + (size_t)bt * 8);
      mp[0] = ulonglong2{m[0], m[1]};
      mp[1] = ulonglong2{m[2], m[3]};
      mp[2] = ulonglong2{m[4], m[5]};
      mp[3] = ulonglong2{m[6], m[7]};
      invbuf[bt] = invcnt;
    }
  }

  cg::this_grid().sync();

  // ========== phase 2: colsum -> coef -> weighted partial sums ==========
  {
    const int chunk = blockIdx.x & (NCHUNK_ - 1);
    const int b = blockIdx.x >> 5;
    const int wi0 = (chunk < 16) ? 0 : 4;
    for (int i = tid; i < S_ * 4; i += 256) {
      const int t = i >> 2, j = i & 3;
      sh.p2.ld[i] = maskbuf[(((size_t)b << 9) + t) * 8 + wi0 + j];
    }
    for (int i = tid; i < S_; i += 256) sh.p2.inv[i] = invbuf[(b << 9) + i];
    __syncthreads();

    if (tid < 128) {
      const int c = tid >> 3, g = tid & 7;     // 16 cols x 8 t-groups
      const int s = chunk * CH_ + c;
      const int j = s & 3;
      const unsigned long long bm = 1ull << ((s & 255) >> 2);
      float w = 0.f;
      #pragma unroll 8
      for (int i = 0; i < 64; ++i) {
        const int t = i * 8 + g;               // interleaved: 2-way LDS max
        if (sh.p2.ld[t * 4 + j] & bm) w += sh.p2.inv[t];
      }
      sh.p2.part[c][g] = w;
    }
    __syncthreads();
    if (tid < CH_) {
      float w = 0.f;
      #pragma unroll
      for (int g = 0; g < 8; ++g) w += sh.p2.part[tid][g];
      const float eta = node_eta[0];
      sh.p2.cs[tid] = (eta + (1.0f - eta) * w) * (1.0f / (float)S_);
    }
    __syncthreads();

    if (tid < 192) {  // d = 4*tid .. 4*tid+3 (D_ = 768)
      const float* hb =
          hidden + ((size_t)b * S_ + (size_t)chunk * CH_) * D_ + 4 * tid;
      float4 acc = make_float4(0.f, 0.f, 0.f, 0.f);
      #pragma unroll
      for (int s = 0; s < CH_; ++s) {
        const float4 v = *(const float4*)(hb + (size_t)s * D_);
        const float c = sh.p2.cs[s];
        acc.x += c * v.x; acc.y += c * v.y; acc.z += c * v.z; acc.w += c * v.w;
      }
      *(float4*)(x_part + ((size_t)chunk * B_ + b) * D_ + 4 * tid) = acc;
    }
  }

  cg::this_grid().sync();

  // ================= phase 3: tail (16 active blocks) =================
  if (blockIdx.x < B_) {
    const int b = blockIdx.x;
    #pragma unroll
    for (int d = tid; d < D_; d += 256) {
      float s = 0.f;
      #pragma unroll 8
      for (int c = 0; c < NCHUNK_; ++c)
        s += x_part[((size_t)c * B_ + b) * D_ + d];
      sh.p3.xs[d] = s;
    }
    __syncthreads();

    float acc = 0.f;
    #pragma unroll 8
    for (int d = 0; d < D_; ++d) acc += sh.p3.xs[d] * W_node[(size_t)d * P_ + tid];
    sh.p3.ts[tid] = tanhf(acc + b_node[tid]);
    __syncthreads();

    float o = 0.f;
    #pragma unroll 8
    for (int q = 0; q < P_; ++q) o += sh.p3.ts[q] * W_fc[(size_t)q * P_ + tid];
    o += b_fc[tid];

    float s = o;
    #pragma unroll
    for (int off = 32; off > 0; off >>= 1) s += __shfl_down(s, off, 64);
    const int wave = tid >> 6, ln = tid & 63;
    if (ln == 0) sh.p3.red[wave] = s;
    __syncthreads();
    const float mu =
        (sh.p3.red[0] + sh.p3.red[1] + sh.p3.red[2] + sh.p3.red[3]) *
        (1.0f / (float)P_);
    __syncthreads();
    const float dv = o - mu;
    float s2 = dv * dv;
    #pragma unroll
    for (int off = 32; off > 0; off >>= 1) s2 += __shfl_down(s2, off, 64);
    if (ln == 0) sh.p3.red[wave] = s2;
    __syncthreads();
    const float var =
        (sh.p3.red[0] + sh.p3.red[1] + sh.p3.red[2] + sh.p3.red[3]) *
        (1.0f / (float)P_);
    const float inv = 1.0f / sqrtf(var + 1e-5f);
    out[b * P_ + tid] = dv * inv * gamma[tid] + beta[tid];
  }
}

extern "C" void kernel_launch(void* const* d_in, const int* in_sizes, int n_in,
                              void* d_out, int out_size, void* d_ws, size_t ws_size,
                              hipStream_t stream) {
  (void)in_sizes; (void)n_in; (void)out_size; (void)ws_size;
  const float* hidden   = (const float*)d_in[0];  // [B,S,D]
  const float* attn     = (const float*)d_in[1];  // [B,H,S,S]
  /* d_in[2] = length (== S, unused) */
  const float* W_node   = (const float*)d_in[3];  // [D,P]
  const float* b_node   = (const float*)d_in[4];  // [P]
  const float* node_eta = (const float*)d_in[5];  // [1]
  const float* W_fc     = (const float*)d_in[6];  // [P,P]
  const float* b_fc     = (const float*)d_in[7];  // [P]
  const float* gamma    = (const float*)d_in[8];  // [P]
  const float* beta     = (const float*)d_in[9];  // [P]
  float* out = (float*)d_out;                     // [B,P] fp32

  // Workspace: every word written before read; no memsets needed.
  unsigned long long* maskbuf = (unsigned long long*)d_ws;   // B*S*8 u64 (512 KB)
  float* invbuf = (float*)(maskbuf + (size_t)B_ * S_ * 8);   // B*S (32 KB)
  float* x_part = invbuf + B_ * S_;                          // NCHUNK*B*D (1.5 MB)

  void* args[] = {
      (void*)&attn, (void*)&hidden, (void*)&W_node, (void*)&b_node,
      (void*)&node_eta, (void*)&W_fc, (void*)&b_fc, (void*)&gamma,
      (void*)&beta, (void*)&out, (void*)&maskbuf, (void*)&invbuf,
      (void*)&x_part};
  hipLaunchCooperativeKernel((const void*)fused_all, dim3(GRID_), dim3(256),
                             args, 0, stream);
}

// Round 4
// 381.786 us; speedup vs baseline: 1.3440x; 1.3440x over previous
//
#include <hip/hip_runtime.h>
#include <math.h>

// Problem constants (B,S,H,D,P fixed by the reference).
#define B_ 16
#define S_ 512
#define H_ 12
#define D_ 768
#define P_ 256
#define K_ 51
#define CH_ 16            // s-rows per k2 chunk
#define NCHUNK_ (S_/CH_)  // 32

// Monotonic float->uint key: larger float <=> larger unsigned.
__device__ __forceinline__ unsigned okey(float f) {
  unsigned u = __float_as_uint(f);
  return (u & 0x80000000u) ? ~u : (u | 0x80000000u);
}

// k1: one WAVE per (b,t) attention row. Head-average (coalesced float4
// streaming), exact top-K select via wave-uniform MSB-first bit bisection on
// ballots (no LDS, no atomics, no waitcnt drains). Emits per-row selection
// bitmask (8x u64, column-interleaved: bit(lane) of word i covers column
// 4*lane+i for i<4, 256+4*lane+(i-4) for i>=4) plus invcnt.
// __launch_bounds__(256, 8): pin VGPR<=64 so 8 blocks/CU (32 waves) resident
// -- the 201 MB streaming read needs max TLP to hide ~900cy HBM latency.
__global__ __launch_bounds__(256, 8) void k1_topk_mask(
    const float* __restrict__ attn, unsigned long long* __restrict__ maskbuf,
    float* __restrict__ invbuf) {
  const int tid = threadIdx.x;
  const int wv = tid >> 6;
  const int lane = tid & 63;
  const int bt = blockIdx.x * 4 + wv;
  const int b = bt >> 9;            // S_ == 512
  const int t = bt & (S_ - 1);

  // --- head-average: lane owns columns {4*lane+i, 256+4*lane+i} ---
  const float* base = attn + (((size_t)b * H_) * S_ + t) * S_;
  float a[8] = {0.f, 0.f, 0.f, 0.f, 0.f, 0.f, 0.f, 0.f};
  #pragma unroll
  for (int h = 0; h < H_; ++h) {
    const float* r = base + (size_t)h * (S_ * S_);
    const float4 u = *(const float4*)(r + 4 * lane);
    const float4 v = *(const float4*)(r + 256 + 4 * lane);
    a[0] += u.x; a[1] += u.y; a[2] += u.z; a[3] += u.w;
    a[4] += v.x; a[5] += v.y; a[6] += v.z; a[7] += v.w;
  }
  unsigned k[8];
  #pragma unroll
  for (int i = 0; i < 8; ++i) {
    a[i] *= (1.0f / (float)H_);
    k[i] = okey(a[i]);
  }

  // --- row-wide positive count via ballots (wave-uniform result) ---
  int p = 0;
  #pragma unroll
  for (int i = 0; i < 8; ++i) p += __popcll(__ballot(a[i] > 0.f));

  bool sel[8];
  float invcnt;
  if (p >= 1 && p < K_) {
    // kept set == all positive entries (all inside the top-K)
    #pragma unroll
    for (int i = 0; i < 8; ++i) sel[i] = (a[i] > 0.f);
    invcnt = 1.0f / (float)p;
  } else {
    // Exact top-K via bitwise radix bisection. Invariant: keys whose bits
    // above the current position exceed `prefix` are already kept; `rem` of
    // the keys matching `prefix` remain to be chosen.
    unsigned prefix = 0;
    int rem = K_;
    bool done = false;
    unsigned dmask = 0, thr = 0;
    for (int bpos = 31; bpos >= 0; --bpos) {
      const unsigned bit = 1u << bpos;
      const unsigned mb = ~(bit - 1u);       // bits bpos..31
      const unsigned cand = prefix | bit;
      int cnt = 0;
      #pragma unroll
      for (int i = 0; i < 8; ++i)
        cnt += __popcll(__ballot((k[i] & mb) == cand));
      if (cnt == rem) { done = true; dmask = mb; thr = cand; break; }
      if (cnt > rem) prefix = cand;
      else rem -= cnt;
    }
    if (done) {
      #pragma unroll
      for (int i = 0; i < 8; ++i) sel[i] = (k[i] & dmask) >= thr;
    } else {
      // Full-key ties at prefix: keep all k > T plus `rem` lowest-index ties
      // (column order: first half before second half, then 4*lane+i order).
      const unsigned T = prefix;
      unsigned long long mm[8];
      #pragma unroll
      for (int i = 0; i < 8; ++i) mm[i] = __ballot(k[i] == T);
      const unsigned long long lt = ((unsigned long long)1 << lane) - 1ull;
      int fh = 0;
      #pragma unroll
      for (int i = 0; i < 4; ++i) fh += __popcll(mm[i]);
      #pragma unroll
      for (int i = 0; i < 8; ++i) {
        sel[i] = (k[i] > T);
        if (k[i] == T) {
          int r = 0;
          if (i < 4) {
            #pragma unroll
            for (int i2 = 0; i2 < 4; ++i2) r += __popcll(mm[i2] & lt);
            for (int i2 = 0; i2 < i; ++i2) r += (int)((mm[i2] >> lane) & 1ull);
          } else {
            r = fh;
            #pragma unroll
            for (int i2 = 4; i2 < 8; ++i2) r += __popcll(mm[i2] & lt);
            for (int i2 = 4; i2 < i; ++i2) r += (int)((mm[i2] >> lane) & 1ull);
          }
          if (r < rem) sel[i] = true;
        }
      }
    }
    invcnt = 1.0f / (float)K_;
  }

  // --- emit selection bitmask + invcnt (plain stores, no atomics) ---
  unsigned long long m[8];
  #pragma unroll
  for (int i = 0; i < 8; ++i) m[i] = __ballot(sel[i]);
  if (lane == 0) {
    ulonglong2* mp = (ulonglong2*)(maskbuf + (size_t)bt * 8);
    mp[0] = ulonglong2{m[0], m[1]};
    mp[1] = ulonglong2{m[2], m[3]};
    mp[2] = ulonglong2{m[4], m[5]};
    mp[3] = ulonglong2{m[6], m[7]};
    invbuf[bt] = invcnt;
  }
}

// k2: fused colsum + weighted partial sum. Block (chunk, b):
//  phase A: stage this b's mask words (the 4 relevant per t) + inv to LDS,
//           compute coef[s] = (eta + (1-eta) * sum_t bit(t,s)*inv[t]) / S
//           for the chunk's 16 columns (bank-conflict-free interleaved t).
//  phase B: x_part[chunk][b][d] = sum_{s in chunk} coef[s] * hidden[b,s,d]
//           (plain float4 stores -- no atomics, no memset needed).
__global__ __launch_bounds__(192) void k2_colsum_wsum(
    const unsigned long long* __restrict__ maskbuf,
    const float* __restrict__ invbuf, const float* __restrict__ node_eta,
    const float* __restrict__ hidden, float* __restrict__ x_part) {
  const int chunk = blockIdx.x;
  const int b = blockIdx.y;
  const int tid = threadIdx.x;
  __shared__ unsigned long long ld[S_ * 4];  // 16 KB: words wi0..wi0+3 per t
  __shared__ float inv[S_];                  // 2 KB
  __shared__ float part[16][8];
  __shared__ float cs[CH_];

  const int wi0 = (chunk < 16) ? 0 : 4;
  for (int i = tid; i < S_ * 4; i += 192) {
    const int t = i >> 2, j = i & 3;
    ld[i] = maskbuf[(((size_t)b << 9) + t) * 8 + wi0 + j];
  }
  for (int i = tid; i < S_; i += 192) inv[i] = invbuf[(b << 9) + i];
  __syncthreads();

  if (tid < 128) {
    const int c = tid >> 3, g = tid & 7;     // 16 cols x 8 t-groups
    const int s = chunk * CH_ + c;
    const int j = s & 3;
    const unsigned long long bm = 1ull << ((s & 255) >> 2);
    float w = 0.f;
    #pragma unroll 8
    for (int i = 0; i < 64; ++i) {
      const int t = i * 8 + g;               // interleaved: 2-way LDS max
      if (ld[t * 4 + j] & bm) w += inv[t];
    }
    part[c][g] = w;
  }
  __syncthreads();
  if (tid < CH_) {
    float w = 0.f;
    #pragma unroll
    for (int g = 0; g < 8; ++g) w += part[tid][g];
    const float eta = node_eta[0];
    cs[tid] = (eta + (1.0f - eta) * w) * (1.0f / (float)S_);
  }
  __syncthreads();

  const float* hb = hidden + ((size_t)b * S_ + (size_t)chunk * CH_) * D_ + 4 * tid;
  float4 acc = make_float4(0.f, 0.f, 0.f, 0.f);
  #pragma unroll
  for (int s = 0; s < CH_; ++s) {
    const float4 v = *(const float4*)(hb + (size_t)s * D_);
    const float c = cs[s];
    acc.x += c * v.x; acc.y += c * v.y; acc.z += c * v.z; acc.w += c * v.w;
  }
  *(float4*)(x_part + ((size_t)chunk * B_ + b) * D_ + 4 * tid) = acc;
}

// k3: full tail per batch row. Block per b (256 threads):
//  xs[d] = sum over 32 chunk partials; t_p = tanh(xs@W_node + b_node);
//  o_p = t@W_fc + b_fc; LayerNorm -> out.
__global__ __launch_bounds__(256) void k3_tail(
    const float* __restrict__ x_part, const float* __restrict__ W_node,
    const float* __restrict__ b_node, const float* __restrict__ W_fc,
    const float* __restrict__ b_fc, const float* __restrict__ gamma,
    const float* __restrict__ beta, float* __restrict__ out) {
  const int b = blockIdx.x;
  const int tid = threadIdx.x;
  __shared__ float xs[D_];
  __shared__ float ts[P_];
  __shared__ float red[4];

  #pragma unroll
  for (int d = tid; d < D_; d += 256) {
    float s = 0.f;
    #pragma unroll 8
    for (int c = 0; c < NCHUNK_; ++c)
      s += x_part[((size_t)c * B_ + b) * D_ + d];
    xs[d] = s;
  }
  __syncthreads();

  float acc = 0.f;
  #pragma unroll 8
  for (int d = 0; d < D_; ++d) acc += xs[d] * W_node[(size_t)d * P_ + tid];
  ts[tid] = tanhf(acc + b_node[tid]);
  __syncthreads();

  float o = 0.f;
  #pragma unroll 8
  for (int q = 0; q < P_; ++q) o += ts[q] * W_fc[(size_t)q * P_ + tid];
  o += b_fc[tid];

  float s = o;
  #pragma unroll
  for (int off = 32; off > 0; off >>= 1) s += __shfl_down(s, off, 64);
  const int wave = tid >> 6, lane = tid & 63;
  if (lane == 0) red[wave] = s;
  __syncthreads();
  const float mu = (red[0] + red[1] + red[2] + red[3]) * (1.0f / (float)P_);
  __syncthreads();
  const float dv = o - mu;
  float s2 = dv * dv;
  #pragma unroll
  for (int off = 32; off > 0; off >>= 1) s2 += __shfl_down(s2, off, 64);
  if (lane == 0) red[wave] = s2;
  __syncthreads();
  const float var = (red[0] + red[1] + red[2] + red[3]) * (1.0f / (float)P_);
  const float inv = 1.0f / sqrtf(var + 1e-5f);
  out[b * P_ + tid] = dv * inv * gamma[tid] + beta[tid];
}

extern "C" void kernel_launch(void* const* d_in, const int* in_sizes, int n_in,
                              void* d_out, int out_size, void* d_ws, size_t ws_size,
                              hipStream_t stream) {
  (void)in_sizes; (void)n_in; (void)out_size; (void)ws_size;
  const float* hidden   = (const float*)d_in[0];  // [B,S,D]
  const float* attn     = (const float*)d_in[1];  // [B,H,S,S]
  /* d_in[2] = length (== S, unused) */
  const float* W_node   = (const float*)d_in[3];  // [D,P]
  const float* b_node   = (const float*)d_in[4];  // [P]
  const float* node_eta = (const float*)d_in[5];  // [1]
  const float* W_fc     = (const float*)d_in[6];  // [P,P]
  const float* b_fc     = (const float*)d_in[7];  // [P]
  const float* gamma    = (const float*)d_in[8];  // [P]
  const float* beta     = (const float*)d_in[9];  // [P]
  float* out = (float*)d_out;                     // [B,P] fp32

  // Workspace layout (16B-aligned pieces, ~2.1 MB total). No memsets needed:
  // every workspace word is written before it is read.
  unsigned long long* maskbuf = (unsigned long long*)d_ws;   // B*S*8 u64 (512 KB)
  float* invbuf = (float*)(maskbuf + (size_t)B_ * S_ * 8);   // B*S (32 KB)
  float* x_part = invbuf + B_ * S_;                          // NCHUNK*B*D (1.5 MB)

  k1_topk_mask<<<(B_ * S_) / 4, 256, 0, stream>>>(attn, maskbuf, invbuf);
  k2_colsum_wsum<<<dim3(NCHUNK_, B_), 192, 0, stream>>>(maskbuf, invbuf,
                                                        node_eta, hidden, x_part);
  k3_tail<<<B_, 256, 0, stream>>>(x_part, W_node, b_node, W_fc, b_fc,
                                  gamma, beta, out);
}